// Round 2
// baseline (393.956 us; speedup 1.0000x reference)
//
#include <hip/hip_runtime.h>
#include <hip/hip_bf16.h>
#include <math.h>

// MP_Attention: B=8,S=1024,E=1024,H=8,hd=128, fp32 in/out, bf16 MFMA internals.

typedef __attribute__((ext_vector_type(4))) float f32x4;
typedef __attribute__((ext_vector_type(4))) short s16x4;
typedef __attribute__((ext_vector_type(8))) short s16x8;

__device__ __forceinline__ short f2bf(float f) {
  union { __hip_bfloat16 h; short s; } u;
  u.h = __float2bfloat16(f);
  return u.s;
}
__device__ __forceinline__ float bf2f(short s) {
  union { short s; __hip_bfloat16 h; } u;
  u.s = s;
  return __bfloat162float(u.h);
}
__device__ __forceinline__ f32x4 mfma16(s16x8 a, s16x8 b, f32x4 c) {
  return __builtin_amdgcn_mfma_f32_16x16x32_bf16(a, b, c, 0, 0, 0);
}

// ---------------- weight norm: wn = w * g / (32*eps + ||row||), bf16 out ----
__global__ __launch_bounds__(256) void k_wnorm(const float* __restrict__ qw, const float* __restrict__ kw,
                                               const float* __restrict__ vw, const float* __restrict__ ow,
                                               const float* __restrict__ gain, short* __restrict__ wn) {
  const int r = blockIdx.x;            // 0..4095 (4 mats x 1024 rows)
  const int mat = r >> 10;
  const float* W = mat == 0 ? qw : mat == 1 ? kw : mat == 2 ? vw : ow;
  const float* src = W + (size_t)(r & 1023) * 1024;
  const int tid = threadIdx.x;
  f32x4 v = *(const f32x4*)&src[tid * 4];
  float s = v[0]*v[0] + v[1]*v[1] + v[2]*v[2] + v[3]*v[3];
  __shared__ float red[256];
  red[tid] = s; __syncthreads();
  for (int off = 128; off > 0; off >>= 1) {
    if (tid < off) red[tid] += red[tid + off];
    __syncthreads();
  }
  const float scale = gain[0] / (0.0032f + sqrtf(red[0]));  // sqrt(1024)*1e-4 + n
  s16x4 o;
  o[0] = f2bf(v[0]*scale); o[1] = f2bf(v[1]*scale);
  o[2] = f2bf(v[2]*scale); o[3] = f2bf(v[3]*scale);
  *(s16x4*)&wn[(size_t)r * 1024 + tid * 4] = o;
}

// ---------------- fp32 -> bf16 convert (vectorized) -------------------------
__global__ __launch_bounds__(256) void k_cvt(const float* __restrict__ in, short* __restrict__ out, int n4) {
  int idx = blockIdx.x * 256 + threadIdx.x;
  int stride = gridDim.x * 256;
  for (int i = idx; i < n4; i += stride) {
    f32x4 v = ((const f32x4*)in)[i];
    s16x4 o;
    o[0] = f2bf(v[0]); o[1] = f2bf(v[1]); o[2] = f2bf(v[2]); o[3] = f2bf(v[3]);
    ((s16x4*)out)[i] = o;
  }
}

// ---------------- QKV GEMM: C = X * WN^T  (z=0:Q, 1:K, 2:V-transposed) ------
// 128x128 tile, BK=64, 4 waves 2x2, padded LDS (72 elem rows) reg-staging.
__global__ __launch_bounds__(256) void k_gemm_qkv(const short* __restrict__ X, const short* __restrict__ WN,
                                                  short* __restrict__ Qb, short* __restrict__ Kb,
                                                  short* __restrict__ Vt) {
  __shared__ short Al[128 * 72];
  __shared__ short Bl[128 * 72];
  const int z = blockIdx.z;
  const short* __restrict__ Wm = WN + (size_t)z * 1048576;
  const int m0 = blockIdx.x * 128, n0 = blockIdx.y * 128;
  const int tid = threadIdx.x, lane = tid & 63, w = tid >> 6;
  const int hi = lane >> 4, ql = lane & 15;
  const int wm = w >> 1, wn_ = w & 1;
  f32x4 acc[4][4];
#pragma unroll
  for (int i = 0; i < 4; i++)
#pragma unroll
    for (int j = 0; j < 4; j++) acc[i][j] = (f32x4){0.f, 0.f, 0.f, 0.f};
  const int srow = tid >> 3, sc8 = (tid & 7) * 8;
  for (int k0 = 0; k0 < 1024; k0 += 64) {
#pragma unroll
    for (int it = 0; it < 4; ++it) {
      int row = srow + it * 32;
      *(s16x8*)&Al[row * 72 + sc8] = *(const s16x8*)&X[(size_t)(m0 + row) * 1024 + k0 + sc8];
      *(s16x8*)&Bl[row * 72 + sc8] = *(const s16x8*)&Wm[(size_t)(n0 + row) * 1024 + k0 + sc8];
    }
    __syncthreads();
#pragma unroll
    for (int kc = 0; kc < 2; ++kc) {
      s16x8 af[4], bfr[4];
#pragma unroll
      for (int i = 0; i < 4; i++) af[i] = *(const s16x8*)&Al[(wm * 64 + i * 16 + ql) * 72 + kc * 32 + 8 * hi];
#pragma unroll
      for (int j = 0; j < 4; j++) bfr[j] = *(const s16x8*)&Bl[(wn_ * 64 + j * 16 + ql) * 72 + kc * 32 + 8 * hi];
#pragma unroll
      for (int i = 0; i < 4; i++)
#pragma unroll
        for (int j = 0; j < 4; j++) acc[i][j] = mfma16(af[i], bfr[j], acc[i][j]);
    }
    __syncthreads();
  }
  if (z == 2) {
    // V: store transposed -> Vt[((b*8+h)*128 + d)*1024 + s]
    const int b = m0 >> 10;
    const int sbase = (m0 & 1023) + wm * 64;
#pragma unroll
    for (int i = 0; i < 4; i++) {
#pragma unroll
      for (int j = 0; j < 4; j++) {
        int ng = n0 + wn_ * 64 + j * 16 + ql;
        int h = ng >> 7, d = ng & 127;
        int s = sbase + i * 16 + 4 * hi;
        s16x4 v;
        v[0] = f2bf(acc[i][j][0]); v[1] = f2bf(acc[i][j][1]);
        v[2] = f2bf(acc[i][j][2]); v[3] = f2bf(acc[i][j][3]);
        *(s16x4*)&Vt[(size_t)((b * 8 + h) * 128 + d) * 1024 + s] = v;
      }
    }
  } else {
    short* __restrict__ C = (z == 0) ? Qb : Kb;
#pragma unroll
    for (int i = 0; i < 4; i++) {
      int mg = m0 + wm * 64 + i * 16 + 4 * hi;
#pragma unroll
      for (int j = 0; j < 4; j++) {
        int ng = n0 + wn_ * 64 + j * 16 + ql;
#pragma unroll
        for (int r = 0; r < 4; r++) C[(size_t)(mg + r) * 1024 + ng] = f2bf(acc[i][j][r]);
      }
    }
  }
}

// ---------------- flash attention, swapped QK^T, 4 waves x 16 q-rows --------
__global__ __launch_bounds__(256) void k_attn(const short* __restrict__ Qb, const short* __restrict__ Kb,
                                              const short* __restrict__ Vt, const short* __restrict__ Bias,
                                              short* __restrict__ Ob) {
  __shared__ short lds[64 * 136 + 128 * 72];
  short* Kl = lds;                 // [64][136] K tile (t rows, d contig, pad 8)
  short* Vl = lds + 64 * 136;      // [128][72] V^T tile (d rows, t contig, pad 8)
  const int bh = blockIdx.y, b = bh >> 3, h = bh & 7;
  const int q0 = blockIdx.x * 64;
  const int tid = threadIdx.x, w = tid >> 6, lane = tid & 63;
  const int hi = lane >> 4, ql = lane & 15;
  const int qrow = q0 + w * 16 + ql;
  const short* __restrict__ qbase = Qb + (size_t)(b * 1024 + qrow) * 1024 + h * 128;
  s16x8 qf[4];
#pragma unroll
  for (int kc = 0; kc < 4; kc++) qf[kc] = *(const s16x8*)&qbase[kc * 32 + 8 * hi];
  float m_run = -INFINITY, l_run = 0.f;
  f32x4 acc[8];
#pragma unroll
  for (int d = 0; d < 8; d++) acc[d] = (f32x4){0.f, 0.f, 0.f, 0.f};
  const float sc = 0.08838834764831845f;  // 1/sqrt(128)
  const float L2E = 1.4426950408889634f;
  // K tile staging: 64 rows x 128 cols -> 16 threads/row x 8 shorts, 4 iters
  const int krow = tid >> 4, kcol = (tid & 15) * 8;
  // V tile staging: 128 rows x 64 cols -> 8 threads/row x 8 shorts, 4 iters
  const int vrow_s = tid >> 3, vcol = (tid & 7) * 8;
  for (int t0 = 0; t0 < 1024; t0 += 64) {
#pragma unroll
    for (int it = 0; it < 4; ++it) {  // K tile: 64 x 128 (FULL d range)
      int row = krow + it * 16;
      *(s16x8*)&Kl[row * 136 + kcol] = *(const s16x8*)&Kb[(size_t)(b * 1024 + t0 + row) * 1024 + h * 128 + kcol];
    }
#pragma unroll
    for (int it = 0; it < 4; ++it) {  // Vt tile: 128 d-rows x 64 t
      int row = vrow_s + it * 32;
      *(s16x8*)&Vl[row * 72 + vcol] = *(const s16x8*)&Vt[(size_t)(bh * 128 + row) * 1024 + t0 + vcol];
    }
    __syncthreads();
    // S^T = K * Q^T : D[t][q], q = lane&15, t = tb*16 + 4*hi + r
    f32x4 st[4];
#pragma unroll
    for (int tb = 0; tb < 4; tb++) {
      st[tb] = (f32x4){0.f, 0.f, 0.f, 0.f};
#pragma unroll
      for (int kc = 0; kc < 4; kc++) {
        s16x8 kf = *(const s16x8*)&Kl[(tb * 16 + ql) * 136 + kc * 32 + 8 * hi];
        st[tb] = mfma16(kf, qf[kc], st[tb]);
      }
    }
    // scale + rel-pos bias + online softmax (per q = ql; lanes 16 apart are replicas)
    float p[4][4];
    float mt = -INFINITY;
#pragma unroll
    for (int tb = 0; tb < 4; tb++) {
      s16x4 bb = *(const s16x4*)&Bias[(size_t)(h * 1024 + qrow) * 1024 + t0 + tb * 16 + 4 * hi];
#pragma unroll
      for (int r = 0; r < 4; r++) {
        float v0 = st[tb][r] * sc + bf2f(bb[r]);
        p[tb][r] = v0;
        mt = fmaxf(mt, v0);
      }
    }
    mt = fmaxf(mt, __shfl_xor(mt, 16));
    mt = fmaxf(mt, __shfl_xor(mt, 32));
    float mnew = fmaxf(m_run, mt);
    float alpha = exp2f((m_run - mnew) * L2E);
    float ps = 0.f;
#pragma unroll
    for (int tb = 0; tb < 4; tb++)
#pragma unroll
      for (int r = 0; r < 4; r++) {
        float e = exp2f((p[tb][r] - mnew) * L2E);
        p[tb][r] = e;
        ps += e;
      }
    ps += __shfl_xor(ps, 16);
    ps += __shfl_xor(ps, 32);
    l_run = l_run * alpha + ps;
    m_run = mnew;
#pragma unroll
    for (int d = 0; d < 8; d++) {
      acc[d][0] *= alpha; acc[d][1] *= alpha; acc[d][2] *= alpha; acc[d][3] *= alpha;
    }
    // pack P^T into B-operand (t = tc*32 + 4*hi + (e&3) + 16*(e>>2)) — lane local
    s16x8 pf[2];
#pragma unroll
    for (int tc = 0; tc < 2; tc++) {
#pragma unroll
      for (int r = 0; r < 4; r++) {
        pf[tc][r] = f2bf(p[2 * tc][r]);
        pf[tc][4 + r] = f2bf(p[2 * tc + 1][r]);
      }
    }
    // O^T += V^T * P^T : per d-block, A = Vt rows (i=d=lane&15), same k-map as B
#pragma unroll
    for (int db = 0; db < 8; db++) {
      const short* vrow = &Vl[(db * 16 + ql) * 72];
#pragma unroll
      for (int tc = 0; tc < 2; tc++) {
        s16x4 lo = *(const s16x4*)&vrow[tc * 32 + 4 * hi];
        s16x4 hi4 = *(const s16x4*)&vrow[tc * 32 + 16 + 4 * hi];
        s16x8 vf;
        vf[0] = lo[0]; vf[1] = lo[1]; vf[2] = lo[2]; vf[3] = lo[3];
        vf[4] = hi4[0]; vf[5] = hi4[1]; vf[6] = hi4[2]; vf[7] = hi4[3];
        acc[db] = mfma16(vf, pf[tc], acc[db]);
      }
    }
    __syncthreads();
  }
  // epilogue: O[q][d] = acc/l, bounce through LDS for coalesced global write
  const float invl = 1.f / l_run;
  short* Ol = lds;  // reuse as [64][136]
#pragma unroll
  for (int db = 0; db < 8; db++) {
    s16x4 v;
    v[0] = f2bf(acc[db][0] * invl); v[1] = f2bf(acc[db][1] * invl);
    v[2] = f2bf(acc[db][2] * invl); v[3] = f2bf(acc[db][3] * invl);
    *(s16x4*)&Ol[(w * 16 + ql) * 136 + db * 16 + 4 * hi] = v;
  }
  __syncthreads();
#pragma unroll
  for (int it = 0; it < 4; ++it) {
    int idx = tid + it * 256;
    int row = idx >> 4, c = idx & 15;
    *(s16x8*)&Ob[(size_t)(b * 1024 + q0 + row) * 1024 + h * 128 + c * 8] = *(const s16x8*)&Ol[row * 136 + c * 8];
  }
}

// ---------------- O-proj GEMM + fused mp_sum residual (fp32 out) ------------
__global__ __launch_bounds__(256) void k_gemm_o(const short* __restrict__ X, const short* __restrict__ Wm,
                                                const float* __restrict__ Qin, float* __restrict__ Out) {
  __shared__ short Al[128 * 72];
  __shared__ short Bl[128 * 72];
  const int m0 = blockIdx.x * 128, n0 = blockIdx.y * 128;
  const int tid = threadIdx.x, lane = tid & 63, w = tid >> 6;
  const int hi = lane >> 4, ql = lane & 15;
  const int wm = w >> 1, wn_ = w & 1;
  f32x4 acc[4][4];
#pragma unroll
  for (int i = 0; i < 4; i++)
#pragma unroll
    for (int j = 0; j < 4; j++) acc[i][j] = (f32x4){0.f, 0.f, 0.f, 0.f};
  const int srow = tid >> 3, sc8 = (tid & 7) * 8;
  for (int k0 = 0; k0 < 1024; k0 += 64) {
#pragma unroll
    for (int it = 0; it < 4; ++it) {
      int row = srow + it * 32;
      *(s16x8*)&Al[row * 72 + sc8] = *(const s16x8*)&X[(size_t)(m0 + row) * 1024 + k0 + sc8];
      *(s16x8*)&Bl[row * 72 + sc8] = *(const s16x8*)&Wm[(size_t)(n0 + row) * 1024 + k0 + sc8];
    }
    __syncthreads();
#pragma unroll
    for (int kc = 0; kc < 2; ++kc) {
      s16x8 af[4], bfr[4];
#pragma unroll
      for (int i = 0; i < 4; i++) af[i] = *(const s16x8*)&Al[(wm * 64 + i * 16 + ql) * 72 + kc * 32 + 8 * hi];
#pragma unroll
      for (int j = 0; j < 4; j++) bfr[j] = *(const s16x8*)&Bl[(wn_ * 64 + j * 16 + ql) * 72 + kc * 32 + 8 * hi];
#pragma unroll
      for (int i = 0; i < 4; i++)
#pragma unroll
        for (int j = 0; j < 4; j++) acc[i][j] = mfma16(af[i], bfr[j], acc[i][j]);
    }
    __syncthreads();
  }
  // out = (query + o @ own^T) * 1/sqrt(2)   [t=0.5 mp_sum]
#pragma unroll
  for (int i = 0; i < 4; i++) {
    int mg = m0 + wm * 64 + i * 16 + 4 * hi;
#pragma unroll
    for (int j = 0; j < 4; j++) {
      int ng = n0 + wn_ * 64 + j * 16 + ql;
#pragma unroll
      for (int r = 0; r < 4; r++) {
        size_t idx = (size_t)(mg + r) * 1024 + ng;
        Out[idx] = (Qin[idx] + acc[i][j][r]) * 0.7071067811865476f;
      }
    }
  }
}

extern "C" void kernel_launch(void* const* d_in, const int* in_sizes, int n_in,
                              void* d_out, int out_size, void* d_ws, size_t ws_size,
                              hipStream_t stream) {
  (void)in_sizes; (void)n_in; (void)out_size; (void)ws_size;
  const float* query = (const float*)d_in[0];
  const float* gain_s = (const float*)d_in[1];
  // d_in[2] = gain_t (unused: time_dim=0)
  const float* qw = (const float*)d_in[3];
  const float* kw = (const float*)d_in[4];
  const float* vw = (const float*)d_in[5];
  const float* ow = (const float*)d_in[6];
  const float* bias = (const float*)d_in[7];
  float* out = (float*)d_out;

  // workspace layout (shorts): total 46,137,344 elems = ~88 MB
  short* ws = (short*)d_ws;
  short* s_wn = ws;                       // 4 x 1M  (q,k,v,o normalized bf16)
  short* s_x  = s_wn + 4 * 1048576;       // 8M  query bf16; REUSED as attn output
  short* s_bb = s_x + 8388608;            // 8M  bias bf16
  short* s_Q  = s_bb + 8388608;           // 8M
  short* s_K  = s_Q + 8388608;            // 8M
  short* s_Vt = s_K + 8388608;            // 8M  V transposed [b][h][d][s]
  short* s_O  = s_x;                      // alias: x dead after QKV GEMM

  k_wnorm<<<dim3(4096), dim3(256), 0, stream>>>(qw, kw, vw, ow, gain_s, s_wn);
  k_cvt<<<dim3(2048), dim3(256), 0, stream>>>(query, s_x, 2097152);
  k_cvt<<<dim3(2048), dim3(256), 0, stream>>>(bias, s_bb, 2097152);
  k_gemm_qkv<<<dim3(64, 8, 3), dim3(256), 0, stream>>>(s_x, s_wn, s_Q, s_K, s_Vt);
  k_attn<<<dim3(16, 64), dim3(256), 0, stream>>>(s_Q, s_K, s_Vt, s_bb, s_O);
  k_gemm_o<<<dim3(64, 8), dim3(256), 0, stream>>>(s_O, s_wn + 3 * 1048576, query, out);
}

// Round 3
// 308.395 us; speedup vs baseline: 1.2774x; 1.2774x over previous
//
#include <hip/hip_runtime.h>
#include <hip/hip_bf16.h>
#include <math.h>

// MP_Attention: B=8,S=1024,E=1024,H=8,hd=128, fp32 in/out, bf16 MFMA internals.
// R3: GEMMs use global_load_lds(16B) + st-swizzle (m97 recipe); attn uses
// reg-prefetch async staging (T14) + swizzled linear LDS + setprio.

typedef __attribute__((ext_vector_type(4))) float f32x4;
typedef __attribute__((ext_vector_type(4))) short s16x4;
typedef __attribute__((ext_vector_type(8))) short s16x8;

__device__ __forceinline__ short f2bf(float f) {
  union { __hip_bfloat16 h; short s; } u;
  u.h = __float2bfloat16(f);
  return u.s;
}
__device__ __forceinline__ float bf2f(short s) {
  union { short s; __hip_bfloat16 h; } u;
  u.s = s;
  return __bfloat162float(u.h);
}
__device__ __forceinline__ f32x4 mfma16(s16x8 a, s16x8 b, f32x4 c) {
  return __builtin_amdgcn_mfma_f32_16x16x32_bf16(a, b, c, 0, 0, 0);
}

typedef __attribute__((address_space(1))) const unsigned int* as1_u32p;
typedef __attribute__((address_space(3))) unsigned int* as3_u32p;
// async global->LDS, 16B/lane; LDS dest = wave-uniform base + lane*16
__device__ __forceinline__ void g2l16(const short* g, short* l) {
  __builtin_amdgcn_global_load_lds((as1_u32p)g, (as3_u32p)l, 16, 0, 0);
}

// ---------------- weight norm: wn = w * g / (sqrt(1024)*eps + ||row||) ------
__global__ __launch_bounds__(256) void k_wnorm(const float* __restrict__ qw, const float* __restrict__ kw,
                                               const float* __restrict__ vw, const float* __restrict__ ow,
                                               const float* __restrict__ gain, short* __restrict__ wn) {
  const int r = blockIdx.x;            // 0..4095 (4 mats x 1024 rows)
  const int mat = r >> 10;
  const float* W = mat == 0 ? qw : mat == 1 ? kw : mat == 2 ? vw : ow;
  const float* src = W + (size_t)(r & 1023) * 1024;
  const int tid = threadIdx.x;
  f32x4 v = *(const f32x4*)&src[tid * 4];
  float s = v[0]*v[0] + v[1]*v[1] + v[2]*v[2] + v[3]*v[3];
  __shared__ float red[256];
  red[tid] = s; __syncthreads();
  for (int off = 128; off > 0; off >>= 1) {
    if (tid < off) red[tid] += red[tid + off];
    __syncthreads();
  }
  const float scale = gain[0] / (0.0032f + sqrtf(red[0]));
  s16x4 o;
  o[0] = f2bf(v[0]*scale); o[1] = f2bf(v[1]*scale);
  o[2] = f2bf(v[2]*scale); o[3] = f2bf(v[3]*scale);
  *(s16x4*)&wn[(size_t)r * 1024 + tid * 4] = o;
}

// ---------------- fp32 -> bf16 convert (vectorized) -------------------------
__global__ __launch_bounds__(256) void k_cvt(const float* __restrict__ in, short* __restrict__ out, int n4) {
  int idx = blockIdx.x * 256 + threadIdx.x;
  int stride = gridDim.x * 256;
  for (int i = idx; i < n4; i += stride) {
    f32x4 v = ((const f32x4*)in)[i];
    s16x4 o;
    o[0] = f2bf(v[0]); o[1] = f2bf(v[1]); o[2] = f2bf(v[2]); o[3] = f2bf(v[3]);
    ((s16x4*)out)[i] = o;
  }
}

// ======== GEMM core loop (m97 structure): 128x128 tile, BK=64, 4 waves ======
// LDS linear [128][64] shorts; 16B-slot swizzle slot^=(row&7), applied on the
// PRE-SWIZZLED global source (write side) and on ds_read (read side).
#define GEMM_K_LOOP(XPTR, WPTR)                                                      \
  const int srw = lane >> 3;          /* 0..7 row-in-chunk */                        \
  const int ssl = lane & 7;           /* 16B slot */                                 \
  const int ql7 = ql & 7;                                                            \
  for (int k0 = 0; k0 < 1024; k0 += 64) {                                            \
    _Pragma("unroll")                                                                \
    for (int i = 0; i < 4; i++) {                                                    \
      const int row = i * 32 + w * 8 + srw;                                          \
      g2l16(&XPTR[(size_t)(m0 + row) * 1024 + k0 + ((ssl ^ srw) << 3)],              \
            &Al[(i * 32 + w * 8) * 64]);                                             \
      g2l16(&WPTR[(size_t)(n0 + row) * 1024 + k0 + ((ssl ^ srw) << 3)],              \
            &Bl[(i * 32 + w * 8) * 64]);                                             \
    }                                                                                \
    __syncthreads();                                                                 \
    _Pragma("unroll")                                                                \
    for (int kc = 0; kc < 2; ++kc) {                                                 \
      s16x8 af[4], bfr[4];                                                           \
      _Pragma("unroll")                                                              \
      for (int i = 0; i < 4; i++) {                                                  \
        const int rA = wm * 64 + i * 16 + ql;                                        \
        af[i] = *(const s16x8*)((const char*)Al + rA * 128 +                         \
                                (((kc * 64 + 16 * hi)) ^ (ql7 << 4)));               \
      }                                                                              \
      _Pragma("unroll")                                                              \
      for (int j = 0; j < 4; j++) {                                                  \
        const int rB = wn_ * 64 + j * 16 + ql;                                       \
        bfr[j] = *(const s16x8*)((const char*)Bl + rB * 128 +                        \
                                 (((kc * 64 + 16 * hi)) ^ (ql7 << 4)));              \
      }                                                                              \
      _Pragma("unroll")                                                              \
      for (int i = 0; i < 4; i++)                                                    \
        _Pragma("unroll")                                                            \
        for (int j = 0; j < 4; j++) acc[i][j] = mfma16(af[i], bfr[j], acc[i][j]);    \
    }                                                                                \
    __syncthreads();                                                                 \
  }

// ---------------- QKV GEMM: C = X * WN^T  (z=0:Q, 1:K, 2:V-transposed) ------
__global__ __launch_bounds__(256) void k_gemm_qkv(const short* __restrict__ X, const short* __restrict__ WN,
                                                  short* __restrict__ Qb, short* __restrict__ Kb,
                                                  short* __restrict__ Vt) {
  __shared__ short Al[128 * 64];
  __shared__ short Bl[128 * 64];
  const int z = blockIdx.z;
  const short* __restrict__ Wm = WN + (size_t)z * 1048576;
  const int m0 = blockIdx.x * 128, n0 = blockIdx.y * 128;
  const int tid = threadIdx.x, lane = tid & 63, w = tid >> 6;
  const int hi = lane >> 4, ql = lane & 15;
  const int wm = w >> 1, wn_ = w & 1;
  f32x4 acc[4][4];
#pragma unroll
  for (int i = 0; i < 4; i++)
#pragma unroll
    for (int j = 0; j < 4; j++) acc[i][j] = (f32x4){0.f, 0.f, 0.f, 0.f};
  GEMM_K_LOOP(X, Wm)
  if (z == 2) {
    // V: store transposed -> Vt[((b*8+h)*128 + d)*1024 + s]
    const int b = m0 >> 10;
    const int sbase = (m0 & 1023) + wm * 64;
#pragma unroll
    for (int i = 0; i < 4; i++) {
#pragma unroll
      for (int j = 0; j < 4; j++) {
        int ng = n0 + wn_ * 64 + j * 16 + ql;
        int h = ng >> 7, d = ng & 127;
        int s = sbase + i * 16 + 4 * hi;
        s16x4 v;
        v[0] = f2bf(acc[i][j][0]); v[1] = f2bf(acc[i][j][1]);
        v[2] = f2bf(acc[i][j][2]); v[3] = f2bf(acc[i][j][3]);
        *(s16x4*)&Vt[(size_t)((b * 8 + h) * 128 + d) * 1024 + s] = v;
      }
    }
  } else {
    short* __restrict__ C = (z == 0) ? Qb : Kb;
#pragma unroll
    for (int i = 0; i < 4; i++) {
      int mg = m0 + wm * 64 + i * 16 + 4 * hi;
#pragma unroll
      for (int j = 0; j < 4; j++) {
        int ng = n0 + wn_ * 64 + j * 16 + ql;
#pragma unroll
        for (int r = 0; r < 4; r++) C[(size_t)(mg + r) * 1024 + ng] = f2bf(acc[i][j][r]);
      }
    }
  }
}

// ---------------- flash attention, async reg-prefetch pipeline --------------
__global__ __launch_bounds__(256) void k_attn(const short* __restrict__ Qb, const short* __restrict__ Kb,
                                              const short* __restrict__ Vt, const short* __restrict__ Bias,
                                              short* __restrict__ Ob) {
  __shared__ short lds[64 * 128 + 128 * 64];   // 32 KB
  short* Kl = lds;                 // [64][128] swizzled (16B slot ^= row&7)
  short* Vl = lds + 64 * 128;      // [128][64] swizzled
  const int bh = blockIdx.y, b = bh >> 3, h = bh & 7;
  const int q0 = blockIdx.x * 64;
  const int tid = threadIdx.x, w = tid >> 6, lane = tid & 63;
  const int hi = lane >> 4, ql = lane & 15, ql7 = ql & 7;
  const int qrow = q0 + w * 16 + ql;
  const short* __restrict__ qbase = Qb + (size_t)(b * 1024 + qrow) * 1024 + h * 128;
  s16x8 qf[4];
#pragma unroll
  for (int kc = 0; kc < 4; kc++) qf[kc] = *(const s16x8*)&qbase[kc * 32 + 8 * hi];
  float m_run = -INFINITY, l_run = 0.f;
  f32x4 acc[8];
#pragma unroll
  for (int d = 0; d < 8; d++) acc[d] = (f32x4){0.f, 0.f, 0.f, 0.f};
  const float sc = 0.08838834764831845f;  // 1/sqrt(128)
  const float L2E = 1.4426950408889634f;
  // staging geometry
  const int krow_ = tid >> 4, kslot = tid & 15;   // K: rows it*16+krow_, 16 slots
  const int vrow_ = tid >> 3, vslot = tid & 7;    // V: rows it*32+vrow_, 8 slots
  const short* __restrict__ Kg = Kb + (size_t)(b * 1024) * 1024 + h * 128;
  const short* __restrict__ Vg = Vt + (size_t)bh * 128 * 1024;
  const short* __restrict__ Bg = Bias + (size_t)(h * 1024 + qrow) * 1024;

  s16x8 krA[4], vrA[4]; s16x4 brA[4];
#define LOADT(KR, VR, BR, T0)                                                          \
  do {                                                                                 \
    _Pragma("unroll")                                                                  \
    for (int i = 0; i < 4; i++)                                                        \
      KR[i] = *(const s16x8*)&Kg[(size_t)((T0) + i * 16 + krow_) * 1024 + kslot * 8];  \
    _Pragma("unroll")                                                                  \
    for (int i = 0; i < 4; i++)                                                        \
      VR[i] = *(const s16x8*)&Vg[(size_t)(i * 32 + vrow_) * 1024 + (T0) + vslot * 8];  \
    _Pragma("unroll")                                                                  \
    for (int t = 0; t < 4; t++)                                                        \
      BR[t] = *(const s16x4*)&Bg[(T0) + t * 16 + 4 * hi];                              \
  } while (0)

  LOADT(krA, vrA, brA, 0);
  for (int it = 0; it < 16; ++it) {
    __syncthreads();   // previous tile's compute done -> LDS free
    // ds_write staged tile (swizzled)
#pragma unroll
    for (int i = 0; i < 4; i++) {
      int row = i * 16 + krow_;
      *(s16x8*)((char*)Kl + row * 256 + ((kslot ^ (row & 7)) << 4)) = krA[i];
    }
#pragma unroll
    for (int i = 0; i < 4; i++) {
      int row = i * 32 + vrow_;
      *(s16x8*)((char*)Vl + row * 128 + ((vslot ^ (row & 7)) << 4)) = vrA[i];
    }
    s16x8 krB[4], vrB[4]; s16x4 brB[4];
    if (it < 15) LOADT(krB, vrB, brB, (it + 1) * 64);   // in flight during compute
    __syncthreads();   // LDS tile ready
    // S^T = K * Q^T : D[t][q], q = lane&15, t = tb*16 + 4*hi + r
    f32x4 st[4];
    __builtin_amdgcn_s_setprio(1);
#pragma unroll
    for (int tb = 0; tb < 4; tb++) {
      st[tb] = (f32x4){0.f, 0.f, 0.f, 0.f};
#pragma unroll
      for (int kc = 0; kc < 4; kc++) {
        s16x8 kf = *(const s16x8*)((const char*)Kl + (tb * 16 + ql) * 256 +
                                   ((kc * 64 + 16 * hi) ^ (ql7 << 4)));
        st[tb] = mfma16(kf, qf[kc], st[tb]);
      }
    }
    __builtin_amdgcn_s_setprio(0);
    // scale + bias + online softmax (per q = ql; lanes 16 apart are replicas)
    float p[4][4];
    float mt = -INFINITY;
#pragma unroll
    for (int tb = 0; tb < 4; tb++) {
#pragma unroll
      for (int r = 0; r < 4; r++) {
        float v0 = st[tb][r] * sc + bf2f(brA[tb][r]);
        p[tb][r] = v0;
        mt = fmaxf(mt, v0);
      }
    }
    mt = fmaxf(mt, __shfl_xor(mt, 16));
    mt = fmaxf(mt, __shfl_xor(mt, 32));
    float mnew = fmaxf(m_run, mt);
    float alpha = exp2f((m_run - mnew) * L2E);
    float ps = 0.f;
#pragma unroll
    for (int tb = 0; tb < 4; tb++)
#pragma unroll
      for (int r = 0; r < 4; r++) {
        float e = exp2f((p[tb][r] - mnew) * L2E);
        p[tb][r] = e;
        ps += e;
      }
    ps += __shfl_xor(ps, 16);
    ps += __shfl_xor(ps, 32);
    l_run = l_run * alpha + ps;
    m_run = mnew;
#pragma unroll
    for (int d = 0; d < 8; d++) {
      acc[d][0] *= alpha; acc[d][1] *= alpha; acc[d][2] *= alpha; acc[d][3] *= alpha;
    }
    // pack P^T (t = tc*32 + 4*hi + (e&3) + 16*(e>>2)) — lane local
    s16x8 pf[2];
#pragma unroll
    for (int tc = 0; tc < 2; tc++) {
#pragma unroll
      for (int r = 0; r < 4; r++) {
        pf[tc][r] = f2bf(p[2 * tc][r]);
        pf[tc][4 + r] = f2bf(p[2 * tc + 1][r]);
      }
    }
    // O^T += V^T * P^T
    __builtin_amdgcn_s_setprio(1);
#pragma unroll
    for (int db = 0; db < 8; db++) {
      const char* vbase = (const char*)Vl + (db * 16 + ql) * 128;
#pragma unroll
      for (int tc = 0; tc < 2; tc++) {
        s16x4 lo  = *(const s16x4*)(vbase + ((tc * 64 + 8 * hi) ^ (ql7 << 4)));
        s16x4 hi4 = *(const s16x4*)(vbase + ((tc * 64 + 32 + 8 * hi) ^ (ql7 << 4)));
        s16x8 vf;
        vf[0] = lo[0]; vf[1] = lo[1]; vf[2] = lo[2]; vf[3] = lo[3];
        vf[4] = hi4[0]; vf[5] = hi4[1]; vf[6] = hi4[2]; vf[7] = hi4[3];
        acc[db] = mfma16(vf, pf[tc], acc[db]);
      }
    }
    __builtin_amdgcn_s_setprio(0);
    if (it < 15) {
#pragma unroll
      for (int i = 0; i < 4; i++) { krA[i] = krB[i]; vrA[i] = vrB[i]; brA[i] = brB[i]; }
    }
  }
  // epilogue: O[q][d] = acc/l, bounce through LDS for coalesced global write
  __syncthreads();   // all waves done reading K/V tiles before LDS reuse
  const float invl = 1.f / l_run;
  short* Ol = lds;  // reuse as [64][136]
#pragma unroll
  for (int db = 0; db < 8; db++) {
    s16x4 v;
    v[0] = f2bf(acc[db][0] * invl); v[1] = f2bf(acc[db][1] * invl);
    v[2] = f2bf(acc[db][2] * invl); v[3] = f2bf(acc[db][3] * invl);
    *(s16x4*)&Ol[(w * 16 + ql) * 136 + db * 16 + 4 * hi] = v;
  }
  __syncthreads();
#pragma unroll
  for (int it = 0; it < 4; ++it) {
    int idx = tid + it * 256;
    int row = idx >> 4, c = idx & 15;
    *(s16x8*)&Ob[(size_t)(b * 1024 + q0 + row) * 1024 + h * 128 + c * 8] = *(const s16x8*)&Ol[row * 136 + c * 8];
  }
}

// ---------------- O-proj GEMM + fused mp_sum residual (fp32 out) ------------
__global__ __launch_bounds__(256) void k_gemm_o(const short* __restrict__ X, const short* __restrict__ Wm,
                                                const float* __restrict__ Qin, float* __restrict__ Out) {
  __shared__ short Al[128 * 64];
  __shared__ short Bl[128 * 64];
  const int m0 = blockIdx.x * 128, n0 = blockIdx.y * 128;
  const int tid = threadIdx.x, lane = tid & 63, w = tid >> 6;
  const int hi = lane >> 4, ql = lane & 15;
  const int wm = w >> 1, wn_ = w & 1;
  f32x4 acc[4][4];
#pragma unroll
  for (int i = 0; i < 4; i++)
#pragma unroll
    for (int j = 0; j < 4; j++) acc[i][j] = (f32x4){0.f, 0.f, 0.f, 0.f};
  GEMM_K_LOOP(X, Wm)
  // out = (query + o @ own^T) * 1/sqrt(2)   [t=0.5 mp_sum]
#pragma unroll
  for (int i = 0; i < 4; i++) {
    int mg = m0 + wm * 64 + i * 16 + 4 * hi;
#pragma unroll
    for (int j = 0; j < 4; j++) {
      int ng = n0 + wn_ * 64 + j * 16 + ql;
#pragma unroll
      for (int r = 0; r < 4; r++) {
        size_t idx = (size_t)(mg + r) * 1024 + ng;
        Out[idx] = (Qin[idx] + acc[i][j][r]) * 0.7071067811865476f;
      }
    }
  }
}

extern "C" void kernel_launch(void* const* d_in, const int* in_sizes, int n_in,
                              void* d_out, int out_size, void* d_ws, size_t ws_size,
                              hipStream_t stream) {
  (void)in_sizes; (void)n_in; (void)out_size; (void)ws_size;
  const float* query = (const float*)d_in[0];
  const float* gain_s = (const float*)d_in[1];
  // d_in[2] = gain_t (unused: time_dim=0)
  const float* qw = (const float*)d_in[3];
  const float* kw = (const float*)d_in[4];
  const float* vw = (const float*)d_in[5];
  const float* ow = (const float*)d_in[6];
  const float* bias = (const float*)d_in[7];
  float* out = (float*)d_out;

  short* ws = (short*)d_ws;
  short* s_wn = ws;                       // 4 x 1M  (q,k,v,o normalized bf16)
  short* s_x  = s_wn + 4 * 1048576;       // 8M  query bf16; REUSED as attn output
  short* s_bb = s_x + 8388608;            // 8M  bias bf16
  short* s_Q  = s_bb + 8388608;           // 8M
  short* s_K  = s_Q + 8388608;            // 8M
  short* s_Vt = s_K + 8388608;            // 8M  V transposed [b][h][d][s]
  short* s_O  = s_x;                      // alias: x dead after QKV GEMM

  k_wnorm<<<dim3(4096), dim3(256), 0, stream>>>(qw, kw, vw, ow, gain_s, s_wn);
  k_cvt<<<dim3(2048), dim3(256), 0, stream>>>(query, s_x, 2097152);
  k_cvt<<<dim3(2048), dim3(256), 0, stream>>>(bias, s_bb, 2097152);
  k_gemm_qkv<<<dim3(64, 8, 3), dim3(256), 0, stream>>>(s_x, s_wn, s_Q, s_K, s_Vt);
  k_attn<<<dim3(16, 64), dim3(256), 0, stream>>>(s_Q, s_K, s_Vt, s_bb, s_O);
  k_gemm_o<<<dim3(64, 8), dim3(256), 0, stream>>>(s_O, s_wn + 3 * 1048576, query, out);
}